// Round 1
// baseline (215.624 us; speedup 1.0000x reference)
//
#include <hip/hip_runtime.h>
#include <math.h>

#define V_CLASSES 100000
#define S_SAMPLED 1000
#define DIM       512
#define BATCH     8192

// -log(expected_count(c)) with log-uniform sampler:
//   p = (log(c+2)-log(c+1))/log(V+1) = log1p(1/(c+1))/log(V+1)
//   E = -expm1(S * log1p(-p));  return -log(E)
__device__ __forceinline__ float neg_log_expected(int c) {
    const float log_vp1 = 11.5129354649f;   // log(100001)
    float p = log1pf(1.0f / (float)(c + 1)) / log_vp1;
    float E = -expm1f((float)S_SAMPLED * log1pf(-p));
    return -logf(E);
}

// ---------------- kernel 0: per-sampled-class bias adjustment ----------------
__global__ __launch_bounds__(256) void adj_kernel(const int* __restrict__ sampled,
                                                  const float* __restrict__ b,
                                                  float* __restrict__ adj) {
    int j = blockIdx.x * 256 + threadIdx.x;
    if (j < S_SAMPLED) {
        int c = sampled[j];
        adj[j] = b[c] + neg_log_expected(c);
    }
}

// ---------------- kernel 1: true logits (one wave per batch row) -------------
__global__ __launch_bounds__(256) void true_logits_kernel(
    const int* __restrict__ y_true, const float* __restrict__ y_pred,
    const float* __restrict__ W, const float* __restrict__ b,
    float* __restrict__ true_out)
{
    int row  = blockIdx.x * 4 + (threadIdx.x >> 6);
    int lane = threadIdx.x & 63;
    int lab  = y_true[row];
    const float4* ap = (const float4*)(y_pred + (size_t)row * DIM);
    const float4* wp = (const float4*)(W + (size_t)lab * DIM);
    float s = 0.f;
#pragma unroll
    for (int u = 0; u < 2; ++u) {
        float4 a = ap[lane + u * 64];
        float4 w = wp[lane + u * 64];
        s += a.x * w.x + a.y * w.y + a.z * w.z + a.w * w.w;
    }
#pragma unroll
    for (int off = 32; off; off >>= 1) s += __shfl_xor(s, off);
    if (lane == 0) true_out[row] = s + b[lab] + neg_log_expected(lab);
}

// ---------------- kernel 2: sampled-logits SGEMM (64x64x16 tiles) ------------
#define BM 64
#define BN 64
#define BK 16

__global__ __launch_bounds__(256) void sgemm_logits(
    const float* __restrict__ A,       // y_pred [BATCH][DIM]
    const float* __restrict__ W,       // [V][DIM]
    const int*   __restrict__ sampled, // [S]
    const float* __restrict__ adj,     // [S]
    const int*   __restrict__ y_true,  // [BATCH]
    float*       __restrict__ logits)  // [BATCH][S]
{
    __shared__ float As[BM][BK + 1];
    __shared__ float Bs[BN][BK + 1];
    __shared__ int   sn[BN];

    int tid = threadIdx.x;
    int m0 = blockIdx.y * BM;
    int n0 = blockIdx.x * BN;

    if (tid < BN) {
        int col = n0 + tid;
        sn[tid] = (col < S_SAMPLED) ? sampled[col] : 0;
    }
    __syncthreads();

    int tx = tid & 15, ty = tid >> 4;
    int lr = tid >> 2;          // row within tile for staging, 0..63
    int lk = (tid & 3) * 4;     // k offset for staging (float4)

    float acc[4][4] = {};

    for (int kc = 0; kc < DIM; kc += BK) {
        float4 av = *(const float4*)(A + (size_t)(m0 + lr) * DIM + kc + lk);
        float4 bv = *(const float4*)(W + (size_t)sn[lr] * DIM + kc + lk);
        As[lr][lk + 0] = av.x; As[lr][lk + 1] = av.y;
        As[lr][lk + 2] = av.z; As[lr][lk + 3] = av.w;
        Bs[lr][lk + 0] = bv.x; Bs[lr][lk + 1] = bv.y;
        Bs[lr][lk + 2] = bv.z; Bs[lr][lk + 3] = bv.w;
        __syncthreads();
#pragma unroll
        for (int k = 0; k < BK; ++k) {
            float a[4], bb[4];
#pragma unroll
            for (int i = 0; i < 4; ++i) a[i] = As[ty * 4 + i][k];
#pragma unroll
            for (int j = 0; j < 4; ++j) bb[j] = Bs[tx * 4 + j][k];
#pragma unroll
            for (int i = 0; i < 4; ++i)
#pragma unroll
                for (int j = 0; j < 4; ++j)
                    acc[i][j] += a[i] * bb[j];
        }
        __syncthreads();
    }

#pragma unroll
    for (int i = 0; i < 4; ++i) {
        int row = m0 + ty * 4 + i;
        int lab = y_true[row];
#pragma unroll
        for (int j = 0; j < 4; ++j) {
            int col = n0 + tx * 4 + j;
            if (col < S_SAMPLED) {
                float v = acc[i][j] + adj[col];
                if (sn[tx * 4 + j] == lab) v -= 1e9f;
                logits[(size_t)row * S_SAMPLED + col] = v;
            }
        }
    }
}

// ---------------- kernel 3: per-row logsumexp (one wave per row) -------------
__global__ __launch_bounds__(256) void lse_kernel(
    const float* __restrict__ logits, const float* __restrict__ true_v,
    float* __restrict__ per_ex)
{
    int row  = blockIdx.x * 4 + (threadIdx.x >> 6);
    int lane = threadIdx.x & 63;
    const float* lp = logits + (size_t)row * S_SAMPLED;
    float t = true_v[row];
    float v[16];
    float mx = t;
#pragma unroll
    for (int u = 0; u < 16; ++u) {
        int j = lane + u * 64;
        v[u] = (j < S_SAMPLED) ? lp[j] : -1e30f;
        mx = fmaxf(mx, v[u]);
    }
#pragma unroll
    for (int off = 32; off; off >>= 1) mx = fmaxf(mx, __shfl_xor(mx, off));
    float s = 0.f;
#pragma unroll
    for (int u = 0; u < 16; ++u) s += expf(v[u] - mx);
    if (lane == 0) s += expf(t - mx);
#pragma unroll
    for (int off = 32; off; off >>= 1) s += __shfl_xor(s, off);
    if (lane == 0) per_ex[row] = mx + logf(s) - t;
}

// ---------------- kernel 4: mean over batch (single block, deterministic) ----
__global__ __launch_bounds__(256) void mean_kernel(const float* __restrict__ per_ex,
                                                   float* __restrict__ out) {
    __shared__ float sm[256];
    float s = 0.f;
    for (int i = threadIdx.x; i < BATCH; i += 256) s += per_ex[i];
    sm[threadIdx.x] = s;
    __syncthreads();
    for (int st = 128; st; st >>= 1) {
        if (threadIdx.x < st) sm[threadIdx.x] += sm[threadIdx.x + st];
        __syncthreads();
    }
    if (threadIdx.x == 0) out[0] = sm[0] / (float)BATCH;
}

extern "C" void kernel_launch(void* const* d_in, const int* in_sizes, int n_in,
                              void* d_out, int out_size, void* d_ws, size_t ws_size,
                              hipStream_t stream) {
    const int*   y_true  = (const int*)d_in[0];
    const float* y_pred  = (const float*)d_in[1];
    const float* W       = (const float*)d_in[2];
    const float* b       = (const float*)d_in[3];
    const int*   sampled = (const int*)d_in[4];

    float* logits = (float*)d_ws;                                // 8192*1000 f32
    float* adj    = logits + (size_t)BATCH * S_SAMPLED;          // 1000 f32 (pad 1024)
    float* true_v = adj + 1024;                                  // 8192 f32
    float* per_ex = true_v + BATCH;                              // 8192 f32

    adj_kernel<<<4, 256, 0, stream>>>(sampled, b, adj);
    true_logits_kernel<<<BATCH / 4, 256, 0, stream>>>(y_true, y_pred, W, b, true_v);
    dim3 g2((S_SAMPLED + BN - 1) / BN, BATCH / BM);
    sgemm_logits<<<g2, 256, 0, stream>>>(y_pred, W, sampled, adj, y_true, logits);
    lse_kernel<<<BATCH / 4, 256, 0, stream>>>(logits, true_v, per_ex);
    mean_kernel<<<1, 256, 0, stream>>>(per_ex, (float*)d_out);
}

// Round 2
// 71.715 us; speedup vs baseline: 3.0067x; 3.0067x over previous
//
#include <hip/hip_runtime.h>
#include <hip/hip_bf16.h>
#include <math.h>

#define V_CLASSES 100000
#define S_SAMPLED 1000
#define SPAD      1024     // padded sampled count
#define DIM       512
#define BATCH     8192

typedef __attribute__((ext_vector_type(8))) short short8_t;  // 8 bf16 = 4 VGPRs
typedef __attribute__((ext_vector_type(4))) float f32x4_t;

__device__ __forceinline__ float neg_log_expected(int c) {
    const float log_vp1 = 11.5129354649f;   // log(100001)
    float p = log1pf(1.0f / (float)(c + 1)) / log_vp1;
    float E = -expm1f((float)S_SAMPLED * log1pf(-p));
    return -logf(E);
}

__device__ __forceinline__ unsigned short f2bf(float x) {
    __hip_bfloat16 h = __float2bfloat16(x);
    union { __hip_bfloat16 h; unsigned short u; } cv; cv.h = h; return cv.u;
}

__device__ __forceinline__ void load_lds16(const void* g, void* l) {
    __builtin_amdgcn_global_load_lds(
        (const __attribute__((address_space(1))) void*)g,
        (__attribute__((address_space(3))) void*)l, 16, 0, 0);
}

// swizzle: flips byte-addr bits 4-6 with bits 7-9 (involution, 16B-granular)
__device__ __forceinline__ int swz(int lin) { return lin ^ (((lin >> 7) & 7) << 4); }

// ---------------- kernel 0: per-sampled-class bias adjustment (padded) -------
__global__ __launch_bounds__(256) void adj_kernel(const int* __restrict__ sampled,
                                                  const float* __restrict__ b,
                                                  float* __restrict__ adj) {
    int j = blockIdx.x * 256 + threadIdx.x;
    if (j >= SPAD) return;
    if (j < S_SAMPLED) {
        int c = sampled[j];
        adj[j] = b[c] + neg_log_expected(c);
    } else {
        adj[j] = -1e30f;   // pad columns contribute exp(-inf)=0
    }
}

// ---------------- kernel 1: cast y_pred f32 -> bf16 (8 elems/thread) ---------
__global__ __launch_bounds__(256) void cast_kernel(const float* __restrict__ in,
                                                   unsigned short* __restrict__ out) {
    int i = (blockIdx.x * 256 + threadIdx.x) * 8;
    float4 f0 = *(const float4*)(in + i);
    float4 f1 = *(const float4*)(in + i + 4);
    uint4 o;
    o.x = (unsigned)f2bf(f0.x) | ((unsigned)f2bf(f0.y) << 16);
    o.y = (unsigned)f2bf(f0.z) | ((unsigned)f2bf(f0.w) << 16);
    o.z = (unsigned)f2bf(f1.x) | ((unsigned)f2bf(f1.y) << 16);
    o.w = (unsigned)f2bf(f1.z) | ((unsigned)f2bf(f1.w) << 16);
    *(uint4*)(out + i) = o;
}

// ---------------- kernel 2: gather + cast W[sampled] -> bf16 [SPAD][DIM] -----
__global__ __launch_bounds__(128) void gather_kernel(const float* __restrict__ W,
                                                     const int* __restrict__ sampled,
                                                     unsigned short* __restrict__ Wg) {
    int row = blockIdx.x;                  // 0..1023
    int t   = threadIdx.x;                 // 128 threads * 4 elems = 512
    unsigned short* dst = Wg + (size_t)row * DIM + t * 4;
    if (row < S_SAMPLED) {
        float4 f = *(const float4*)(W + (size_t)sampled[row] * DIM + t * 4);
        ushort4 o;
        o.x = f2bf(f.x); o.y = f2bf(f.y); o.z = f2bf(f.z); o.w = f2bf(f.w);
        *(ushort4*)dst = o;
    } else {
        *(ushort4*)dst = make_ushort4(0, 0, 0, 0);
    }
}

// ---------------- kernel 3: true logits (f32 exact, one wave per row) --------
__global__ __launch_bounds__(256) void true_logits_kernel(
    const int* __restrict__ y_true, const float* __restrict__ y_pred,
    const float* __restrict__ W, const float* __restrict__ b,
    float* __restrict__ true_out)
{
    int row  = blockIdx.x * 4 + (threadIdx.x >> 6);
    int lane = threadIdx.x & 63;
    int lab  = y_true[row];
    const float4* ap = (const float4*)(y_pred + (size_t)row * DIM);
    const float4* wp = (const float4*)(W + (size_t)lab * DIM);
    float s = 0.f;
#pragma unroll
    for (int u = 0; u < 2; ++u) {
        float4 a = ap[lane + u * 64];
        float4 w = wp[lane + u * 64];
        s += a.x * w.x + a.y * w.y + a.z * w.z + a.w * w.w;
    }
#pragma unroll
    for (int off = 32; off; off >>= 1) s += __shfl_xor(s, off);
    if (lane == 0) true_out[row] = s + b[lab] + neg_log_expected(lab);
}

// ---------------- kernel 4: fused bf16 MFMA GEMM + row LSE -------------------
// BM=32, BN=1024(=SPAD), BK=32, 256 threads = 4 waves.
// Wave w owns cols [w*256, (w+1)*256), all 32 rows. acc = 2 Mfrag x 16 Nfrag.
#define BK 32
#define KTILES (DIM / BK)

__global__ __launch_bounds__(256, 2) void gemm_lse_kernel(
    const unsigned short* __restrict__ Abf,   // y_pred bf16 [BATCH][DIM]
    const unsigned short* __restrict__ Wg,    // gathered W bf16 [SPAD][DIM]
    const int*   __restrict__ sampled,
    const float* __restrict__ adj,
    const int*   __restrict__ y_true,
    const float* __restrict__ true_v,
    float*       __restrict__ per_ex)
{
    // LDS: Bs 64KB | As 2KB | redmax 512B | redsum 512B | mall 128B
    __shared__ __align__(16) char smem[64 * 1024 + 2 * 1024 + 512 + 512 + 128];
    char* Bs = smem;
    char* As = smem + 64 * 1024;
    float* redmax = (float*)(smem + 66 * 1024);
    float* redsum = redmax + 4 * 32;
    float* mall   = redsum + 4 * 32;

    const int tid  = threadIdx.x;
    const int lane = tid & 63;
    const int wid  = tid >> 6;
    const int g    = lane >> 4;     // 16-lane group 0..3
    const int lcol = lane & 15;
    const int m0   = blockIdx.x * 32;

    const char* AbfB = (const char*)Abf;
    const char* WgB  = (const char*)Wg;

    // ---- precompute staging source offsets (constant across K-tiles) ----
    int b_goff[16];
#pragma unroll
    for (int it = 0; it < 16; ++it) {
        int d  = it * 4096 + wid * 1024 + lane * 16;
        int ds = swz(d);
        int col = ds >> 6;          // 0..1023
        int kb  = ds & 63;
        b_goff[it] = col * (DIM * 2) + kb;
    }
    int a_goff[2];
#pragma unroll
    for (int it = 0; it < 2; ++it) {
        int d  = it * 1024 + lane * 16;
        int ds = swz(d);
        int row = ds >> 6;          // 0..31
        int kb  = ds & 63;
        a_goff[it] = (m0 + row) * (DIM * 2) + kb;
    }
    // ---- precompute swizzled ds_read offsets ----
    int a_roff[2], b_roff[16];
#pragma unroll
    for (int mi = 0; mi < 2; ++mi) {
        int lin = (mi * 16 + lcol) * 64 + g * 16;
        a_roff[mi] = swz(lin);
    }
#pragma unroll
    for (int nj = 0; nj < 16; ++nj) {
        int c = wid * 256 + nj * 16 + lcol;
        int lin = c * 64 + g * 16;
        b_roff[nj] = swz(lin);
    }

    f32x4_t acc[2][16] = {};

    // ---- K loop ----
    for (int kt = 0; kt < KTILES; ++kt) {
        const int kcb = kt * (BK * 2);   // byte offset along K
        // stage B tile: 1024 cols x 32 k x bf16 = 64KB
#pragma unroll
        for (int it = 0; it < 16; ++it)
            load_lds16(WgB + b_goff[it] + kcb, Bs + it * 4096 + wid * 1024);
        // stage A tile: 32 rows x 32 k = 2KB (wave 0)
        if (wid == 0) {
#pragma unroll
            for (int it = 0; it < 2; ++it)
                load_lds16(AbfB + a_goff[it] + kcb, As + it * 1024);
        }
        __syncthreads();

        short8_t af0 = *(const short8_t*)(As + a_roff[0]);
        short8_t af1 = *(const short8_t*)(As + a_roff[1]);
#pragma unroll
        for (int nj = 0; nj < 16; ++nj) {
            short8_t bf = *(const short8_t*)(Bs + b_roff[nj]);
            acc[0][nj] = __builtin_amdgcn_mfma_f32_16x16x32_bf16(af0, bf, acc[0][nj], 0, 0, 0);
            acc[1][nj] = __builtin_amdgcn_mfma_f32_16x16x32_bf16(af1, bf, acc[1][nj], 0, 0, 0);
        }
        __syncthreads();
    }

    // ---- epilogue: adj + hit-mask, then fused row-wise logsumexp ----
    // C layout (m89-verified): col = lane&15, row = (lane>>4)*4 + reg
    int   labs[2][4];
    float mrow[2][4];
#pragma unroll
    for (int mi = 0; mi < 2; ++mi)
#pragma unroll
        for (int r = 0; r < 4; ++r) {
            labs[mi][r] = y_true[m0 + mi * 16 + g * 4 + r];
            mrow[mi][r] = -1e30f;
        }

#pragma unroll
    for (int mi = 0; mi < 2; ++mi)
#pragma unroll
        for (int nj = 0; nj < 16; ++nj) {
            int col = wid * 256 + nj * 16 + lcol;
            float aj = adj[col];
            int sc = (col < S_SAMPLED) ? sampled[col] : -1;
            f32x4_t v = acc[mi][nj];
#pragma unroll
            for (int r = 0; r < 4; ++r) {
                float x = v[r] + aj;
                if (sc == labs[mi][r]) x -= 1e9f;
                v[r] = x;
                mrow[mi][r] = fmaxf(mrow[mi][r], x);
            }
            acc[mi][nj] = v;
        }

    // per-row max across the wave's 16 col-lanes
#pragma unroll
    for (int s = 1; s < 16; s <<= 1)
#pragma unroll
        for (int mi = 0; mi < 2; ++mi)
#pragma unroll
            for (int r = 0; r < 4; ++r)
                mrow[mi][r] = fmaxf(mrow[mi][r], __shfl_xor(mrow[mi][r], s));
    if (lcol == 0) {
#pragma unroll
        for (int mi = 0; mi < 2; ++mi)
#pragma unroll
            for (int r = 0; r < 4; ++r)
                redmax[wid * 32 + mi * 16 + g * 4 + r] = mrow[mi][r];
    }
    __syncthreads();
    if (tid < 32) {
        float m = fmaxf(fmaxf(redmax[tid], redmax[32 + tid]),
                        fmaxf(redmax[64 + tid], redmax[96 + tid]));
        m = fmaxf(m, true_v[m0 + tid]);
        mall[tid] = m;
    }
    __syncthreads();

    float srow[2][4];
#pragma unroll
    for (int mi = 0; mi < 2; ++mi)
#pragma unroll
        for (int r = 0; r < 4; ++r) {
            float m = mall[mi * 16 + g * 4 + r];
            float s = 0.f;
#pragma unroll
            for (int nj = 0; nj < 16; ++nj)
                s += expf(acc[mi][nj][r] - m);
            srow[mi][r] = s;
        }
#pragma unroll
    for (int s = 1; s < 16; s <<= 1)
#pragma unroll
        for (int mi = 0; mi < 2; ++mi)
#pragma unroll
            for (int r = 0; r < 4; ++r)
                srow[mi][r] += __shfl_xor(srow[mi][r], s);
    if (lcol == 0) {
#pragma unroll
        for (int mi = 0; mi < 2; ++mi)
#pragma unroll
            for (int r = 0; r < 4; ++r)
                redsum[wid * 32 + mi * 16 + g * 4 + r] = srow[mi][r];
    }
    __syncthreads();
    if (tid < 32) {
        float m = mall[tid];
        float t = true_v[m0 + tid];
        float s = redsum[tid] + redsum[32 + tid] + redsum[64 + tid] + redsum[96 + tid];
        s += expf(t - m);
        per_ex[m0 + tid] = m + logf(s) - t;
    }
}

// ---------------- kernel 5: mean over batch (single block, deterministic) ----
__global__ __launch_bounds__(256) void mean_kernel(const float* __restrict__ per_ex,
                                                   float* __restrict__ out) {
    __shared__ float sm[256];
    float s = 0.f;
    for (int i = threadIdx.x; i < BATCH; i += 256) s += per_ex[i];
    sm[threadIdx.x] = s;
    __syncthreads();
    for (int st = 128; st; st >>= 1) {
        if (threadIdx.x < st) sm[threadIdx.x] += sm[threadIdx.x + st];
        __syncthreads();
    }
    if (threadIdx.x == 0) out[0] = sm[0] / (float)BATCH;
}

extern "C" void kernel_launch(void* const* d_in, const int* in_sizes, int n_in,
                              void* d_out, int out_size, void* d_ws, size_t ws_size,
                              hipStream_t stream) {
    const int*   y_true  = (const int*)d_in[0];
    const float* y_pred  = (const float*)d_in[1];
    const float* W       = (const float*)d_in[2];
    const float* b       = (const float*)d_in[3];
    const int*   sampled = (const int*)d_in[4];

    char* ws = (char*)d_ws;
    unsigned short* ypredB = (unsigned short*)ws;                       // 8 MB
    unsigned short* Wg     = (unsigned short*)(ws + 8 * 1024 * 1024);   // 1 MB
    float* adj    = (float*)(ws + 9 * 1024 * 1024 + 512 * 1024);        // 4 KB
    float* true_v = adj + SPAD;                                         // 32 KB
    float* per_ex = true_v + BATCH;                                     // 32 KB

    adj_kernel<<<SPAD / 256, 256, 0, stream>>>(sampled, b, adj);
    cast_kernel<<<(BATCH * DIM / 8) / 256, 256, 0, stream>>>(y_pred, ypredB);
    gather_kernel<<<SPAD, 128, 0, stream>>>(W, sampled, Wg);
    true_logits_kernel<<<BATCH / 4, 256, 0, stream>>>(y_true, y_pred, W, b, true_v);
    gemm_lse_kernel<<<BATCH / 32, 256, 0, stream>>>(ypredB, Wg, sampled, adj,
                                                    y_true, true_v, per_ex);
    mean_kernel<<<1, 256, 0, stream>>>(per_ex, (float*)d_out);
}

// Round 3
// 43.267 us; speedup vs baseline: 4.9835x; 1.6575x over previous
//
#include <hip/hip_runtime.h>
#include <hip/hip_bf16.h>
#include <math.h>

#define S_SAMPLED 1000
#define SPAD      1024
#define DIM       512
#define BATCH     8192

#define BM 128
#define BN 256
#define BKT 64                 // K per tile (bytes: 128)
#define KTILES (DIM / BKT)     // 8
#define NCHUNK 4               // SPAD / BN

typedef __attribute__((ext_vector_type(8))) short short8_t;  // 8 bf16
typedef __attribute__((ext_vector_type(4))) float f32x4_t;

__device__ __forceinline__ float neg_log_expected(int c) {
    const float log_vp1 = 11.5129354649f;   // log(100001)
    float p = log1pf(1.0f / (float)(c + 1)) / log_vp1;
    float E = -expm1f((float)S_SAMPLED * log1pf(-p));
    return -logf(E);
}

__device__ __forceinline__ unsigned short f2bf(float x) {
    __hip_bfloat16 h = __float2bfloat16(x);
    union { __hip_bfloat16 h; unsigned short u; } cv; cv.h = h; return cv.u;
}

__device__ __forceinline__ void load_lds16(const void* g, void* l) {
    __builtin_amdgcn_global_load_lds(
        (const __attribute__((address_space(1))) void*)g,
        (__attribute__((address_space(3))) void*)l, 16, 0, 0);
}

// involution on byte addr: bits 4-6 ^= row&7 (rows are 128B apart)
__device__ __forceinline__ int swz(int lin) { return lin ^ (((lin >> 7) & 7) << 4); }

// ------------- kernel 0: gather+cast W[sampled] -> bf16, and adj ------------
__global__ __launch_bounds__(128) void gather_adj_kernel(
    const float* __restrict__ W, const int* __restrict__ sampled,
    const float* __restrict__ b, unsigned short* __restrict__ Wg,
    float* __restrict__ adj)
{
    int row = blockIdx.x;                  // 0..1023
    int t   = threadIdx.x;                 // 128 threads * 4 elems = 512
    if (t == 0) {
        if (row < S_SAMPLED) {
            int c = sampled[row];
            adj[row] = b[c] + neg_log_expected(c);
        } else adj[row] = -1e30f;
    }
    unsigned short* dst = Wg + (size_t)row * DIM + t * 4;
    if (row < S_SAMPLED) {
        float4 f = *(const float4*)(W + (size_t)sampled[row] * DIM + t * 4);
        ushort4 o;
        o.x = f2bf(f.x); o.y = f2bf(f.y); o.z = f2bf(f.z); o.w = f2bf(f.w);
        *(ushort4*)dst = o;
    } else {
        *(ushort4*)dst = make_ushort4(0, 0, 0, 0);
    }
}

// ------------- kernel 1: true logits (f32) + y_pred cast to bf16 ------------
__global__ __launch_bounds__(256) void true_cast_kernel(
    const int* __restrict__ y_true, const float* __restrict__ y_pred,
    const float* __restrict__ W, const float* __restrict__ b,
    float* __restrict__ true_out, unsigned short* __restrict__ ypredB)
{
    int row  = blockIdx.x * 4 + (threadIdx.x >> 6);
    int lane = threadIdx.x & 63;
    int lab  = y_true[row];
    const float4* ap = (const float4*)(y_pred + (size_t)row * DIM);
    const float4* wp = (const float4*)(W + (size_t)lab * DIM);
    float s = 0.f;
#pragma unroll
    for (int u = 0; u < 2; ++u) {
        float4 a = ap[lane + u * 64];
        float4 w = wp[lane + u * 64];
        s += a.x * w.x + a.y * w.y + a.z * w.z + a.w * w.w;
        ushort4 o;
        o.x = f2bf(a.x); o.y = f2bf(a.y); o.z = f2bf(a.z); o.w = f2bf(a.w);
        *(ushort4*)(ypredB + (size_t)row * DIM + (lane + u * 64) * 4) = o;
    }
#pragma unroll
    for (int off = 32; off; off >>= 1) s += __shfl_xor(s, off);
    if (lane == 0) true_out[row] = s + b[lab] + neg_log_expected(lab);
}

// ------------- kernel 2: MFMA GEMM + per-chunk partial LSE ------------------
// grid (NCHUNK=4, BATCH/BM=64), 512 threads = 8 waves (WARPS_M=4, WARPS_N=2).
// Wave (wr,wc): rows wr*32+{0..31}, cols wc*128+{0..127}. acc = 2x8 f32x4.
__global__ __launch_bounds__(512, 2) void gemm_partial_kernel(
    const unsigned short* __restrict__ Abf,   // y_pred bf16 [BATCH][DIM]
    const unsigned short* __restrict__ Wg,    // gathered W bf16 [SPAD][DIM]
    const int*   __restrict__ sampled,
    const float* __restrict__ adj,
    const int*   __restrict__ y_true,
    float*       __restrict__ pmax,           // [BATCH][NCHUNK]
    float*       __restrict__ psum)           // [BATCH][NCHUNK]
{
    // LDS: As dbuf 2x16KB | Bs dbuf 2x32KB | redm 2x128 f32 | reds 2x128 f32
    __shared__ __align__(16) char smem[98304 + 2048];
    char* As0 = smem;
    char* As1 = smem + 16384;
    char* Bs0 = smem + 32768;
    char* Bs1 = smem + 65536;
    float* redm = (float*)(smem + 98304);          // [2][128]
    float* reds = (float*)(smem + 98304 + 1024);   // [2][128]

    const int tid  = threadIdx.x;
    const int lane = tid & 63;
    const int wid  = tid >> 6;
    const int wr   = wid >> 1;
    const int wc   = wid & 1;
    const int g    = lane >> 4;
    const int lcol = lane & 15;
    const int m0   = blockIdx.y * BM;
    const int n0   = blockIdx.x * BN;

    const char* AB = (const char*)Abf;
    const char* WB = (const char*)Wg;

    // staging sources: LDS slot d = it*8192 + tid*16 (linear dest), source is
    // the logical position swz(d) (involution) so swizzled reads see data.
    int a_src[2], b_src[4];
#pragma unroll
    for (int it = 0; it < 2; ++it) {
        int d = it * 8192 + tid * 16;
        int row = d >> 7;
        int kb  = (d & 127) ^ ((row & 7) << 4);
        a_src[it] = (m0 + row) * (DIM * 2) + kb;
    }
#pragma unroll
    for (int it = 0; it < 4; ++it) {
        int d = it * 8192 + tid * 16;
        int col = d >> 7;
        int kb  = (d & 127) ^ ((col & 7) << 4);
        b_src[it] = (n0 + col) * (DIM * 2) + kb;
    }

    // swizzled ds_read offsets
    int a_roff[2][2], b_roff[8][2];
#pragma unroll
    for (int mi = 0; mi < 2; ++mi)
#pragma unroll
        for (int ks = 0; ks < 2; ++ks)
            a_roff[mi][ks] = swz((wr * 32 + mi * 16 + lcol) * 128 + ks * 64 + g * 16);
#pragma unroll
    for (int nj = 0; nj < 8; ++nj)
#pragma unroll
        for (int ks = 0; ks < 2; ++ks)
            b_roff[nj][ks] = swz((wc * 128 + nj * 16 + lcol) * 128 + ks * 64 + g * 16);

    f32x4_t acc[2][8] = {};

#define STAGE(AsP, BsP, kt) do {                                     \
        int kb_ = (kt) * (BKT * 2);                                  \
        load_lds16(AB + a_src[0] + kb_, (AsP) + wid * 1024);         \
        load_lds16(AB + a_src[1] + kb_, (AsP) + 8192 + wid * 1024);  \
        load_lds16(WB + b_src[0] + kb_, (BsP) + wid * 1024);         \
        load_lds16(WB + b_src[1] + kb_, (BsP) + 8192 + wid * 1024);  \
        load_lds16(WB + b_src[2] + kb_, (BsP) + 16384 + wid * 1024); \
        load_lds16(WB + b_src[3] + kb_, (BsP) + 24576 + wid * 1024); \
    } while (0)

#define COMPUTE(AsP, BsP) do {                                                        \
        _Pragma("unroll")                                                             \
        for (int ks = 0; ks < 2; ++ks) {                                              \
            short8_t a0 = *(const short8_t*)((AsP) + a_roff[0][ks]);                  \
            short8_t a1 = *(const short8_t*)((AsP) + a_roff[1][ks]);                  \
            _Pragma("unroll")                                                         \
            for (int nj = 0; nj < 8; ++nj) {                                          \
                short8_t bv = *(const short8_t*)((BsP) + b_roff[nj][ks]);             \
                acc[0][nj] = __builtin_amdgcn_mfma_f32_16x16x32_bf16(a0, bv, acc[0][nj], 0, 0, 0); \
                acc[1][nj] = __builtin_amdgcn_mfma_f32_16x16x32_bf16(a1, bv, acc[1][nj], 0, 0, 0); \
            }                                                                         \
        }                                                                             \
    } while (0)

    STAGE(As0, Bs0, 0);
    __syncthreads();
#pragma unroll
    for (int kp = 0; kp < KTILES / 2; ++kp) {
        int kt = kp * 2;
        if (kt + 1 < KTILES) STAGE(As1, Bs1, kt + 1);
        COMPUTE(As0, Bs0);
        __syncthreads();
        if (kt + 2 < KTILES) STAGE(As0, Bs0, kt + 2);
        COMPUTE(As1, Bs1);
        __syncthreads();
    }

    // ---- epilogue: adj + hit mask, per-chunk partial (max, sumexp) ----
    // C layout: col = lane&15, row = (lane>>4)*4 + r
    int   labs[2][4];
    float mrow[2][4];
#pragma unroll
    for (int mi = 0; mi < 2; ++mi)
#pragma unroll
        for (int r = 0; r < 4; ++r) {
            labs[mi][r] = y_true[m0 + wr * 32 + mi * 16 + g * 4 + r];
            mrow[mi][r] = -3e38f;
        }

    float ajv[8]; int scv[8];
#pragma unroll
    for (int nj = 0; nj < 8; ++nj) {
        int cg = n0 + wc * 128 + nj * 16 + lcol;
        ajv[nj] = adj[cg];
        scv[nj] = (cg < S_SAMPLED) ? sampled[cg] : -2147483647;
    }

#pragma unroll
    for (int mi = 0; mi < 2; ++mi)
#pragma unroll
        for (int nj = 0; nj < 8; ++nj) {
            f32x4_t v = acc[mi][nj];
#pragma unroll
            for (int r = 0; r < 4; ++r) {
                float x = v[r] + ajv[nj];
                if (scv[nj] == labs[mi][r]) x -= 1e9f;
                v[r] = x;
                mrow[mi][r] = fmaxf(mrow[mi][r], x);
            }
            acc[mi][nj] = v;
        }

#pragma unroll
    for (int s = 1; s < 16; s <<= 1)
#pragma unroll
        for (int mi = 0; mi < 2; ++mi)
#pragma unroll
            for (int r = 0; r < 4; ++r)
                mrow[mi][r] = fmaxf(mrow[mi][r], __shfl_xor(mrow[mi][r], s));
    if (lcol == 0) {
#pragma unroll
        for (int mi = 0; mi < 2; ++mi)
#pragma unroll
            for (int r = 0; r < 4; ++r)
                redm[wc * 128 + wr * 32 + mi * 16 + g * 4 + r] = mrow[mi][r];
    }
    __syncthreads();

    float srow[2][4];
#pragma unroll
    for (int mi = 0; mi < 2; ++mi)
#pragma unroll
        for (int r = 0; r < 4; ++r) {
            int row = wr * 32 + mi * 16 + g * 4 + r;
            float cm = fmaxf(redm[row], redm[128 + row]);
            float s = 0.f;
#pragma unroll
            for (int nj = 0; nj < 8; ++nj)
                s += expf(acc[mi][nj][r] - cm);
            srow[mi][r] = s;
        }
#pragma unroll
    for (int s = 1; s < 16; s <<= 1)
#pragma unroll
        for (int mi = 0; mi < 2; ++mi)
#pragma unroll
            for (int r = 0; r < 4; ++r)
                srow[mi][r] += __shfl_xor(srow[mi][r], s);
    if (lcol == 0) {
#pragma unroll
        for (int mi = 0; mi < 2; ++mi)
#pragma unroll
            for (int r = 0; r < 4; ++r)
                reds[wc * 128 + wr * 32 + mi * 16 + g * 4 + r] = srow[mi][r];
    }
    __syncthreads();

    if (tid < BM) {
        int row = tid;
        float pm = fmaxf(redm[row], redm[128 + row]);
        float ps = reds[row] + reds[128 + row];
        pmax[(size_t)(m0 + row) * NCHUNK + blockIdx.x] = pm;
        psum[(size_t)(m0 + row) * NCHUNK + blockIdx.x] = ps;
    }
#undef STAGE
#undef COMPUTE
}

// ------------- kernel 3: merge partials + mean (single block) ---------------
__global__ __launch_bounds__(1024) void finalize_kernel(
    const float* __restrict__ pmax, const float* __restrict__ psum,
    const float* __restrict__ true_v, float* __restrict__ out)
{
    __shared__ float sm[1024];
    float tot = 0.f;
#pragma unroll
    for (int u = 0; u < BATCH / 1024; ++u) {
        int r = u * 1024 + threadIdx.x;
        float4 pm = *(const float4*)(pmax + (size_t)r * 4);
        float4 ps = *(const float4*)(psum + (size_t)r * 4);
        float t = true_v[r];
        float m = fmaxf(fmaxf(fmaxf(pm.x, pm.y), fmaxf(pm.z, pm.w)), t);
        float s = ps.x * expf(pm.x - m) + ps.y * expf(pm.y - m)
                + ps.z * expf(pm.z - m) + ps.w * expf(pm.w - m)
                + expf(t - m);
        tot += m + logf(s) - t;
    }
    sm[threadIdx.x] = tot;
    __syncthreads();
    for (int st = 512; st; st >>= 1) {
        if (threadIdx.x < st) sm[threadIdx.x] += sm[threadIdx.x + st];
        __syncthreads();
    }
    if (threadIdx.x == 0) out[0] = sm[0] / (float)BATCH;
}

extern "C" void kernel_launch(void* const* d_in, const int* in_sizes, int n_in,
                              void* d_out, int out_size, void* d_ws, size_t ws_size,
                              hipStream_t stream) {
    const int*   y_true  = (const int*)d_in[0];
    const float* y_pred  = (const float*)d_in[1];
    const float* W       = (const float*)d_in[2];
    const float* b       = (const float*)d_in[3];
    const int*   sampled = (const int*)d_in[4];

    char* ws = (char*)d_ws;
    unsigned short* ypredB = (unsigned short*)ws;                        // 8 MB
    unsigned short* Wg     = (unsigned short*)(ws + 8388608);            // 1 MB
    float* adj    = (float*)(ws + 9437184);                              // 4 KB
    float* true_v = (float*)(ws + 9441280);                              // 32 KB
    float* pmax   = (float*)(ws + 9474048);                              // 128 KB
    float* psum   = (float*)(ws + 9605120);                              // 128 KB

    gather_adj_kernel<<<SPAD, 128, 0, stream>>>(W, sampled, b, Wg, adj);
    true_cast_kernel<<<BATCH / 4, 256, 0, stream>>>(y_true, y_pred, W, b, true_v, ypredB);
    gemm_partial_kernel<<<dim3(NCHUNK, BATCH / BM), 512, 0, stream>>>(
        ypredB, Wg, sampled, adj, y_true, pmax, psum);
    finalize_kernel<<<1, 1024, 0, stream>>>(pmax, psum, true_v, (float*)d_out);
}

// Round 4
// 38.109 us; speedup vs baseline: 5.6581x; 1.1354x over previous
//
#include <hip/hip_runtime.h>
#include <hip/hip_bf16.h>
#include <math.h>

#define S_SAMPLED 1000
#define SPAD      1024
#define DIM       512
#define BATCH     8192

#define BM 128
#define BN 256
#define BKT 64                 // K per tile (128 bytes)
#define KTILES (DIM / BKT)     // 8
#define NCHUNK 4               // SPAD / BN

typedef __attribute__((ext_vector_type(8))) short short8_t;  // 8 bf16
typedef __attribute__((ext_vector_type(4))) float f32x4_t;

__device__ __forceinline__ float neg_log_expected(int c) {
    const float log_vp1 = 11.5129354649f;   // log(100001)
    float p = log1pf(1.0f / (float)(c + 1)) / log_vp1;
    float E = -expm1f((float)S_SAMPLED * log1pf(-p));
    return -logf(E);
}

__device__ __forceinline__ unsigned short f2bf(float x) {
    __hip_bfloat16 h = __float2bfloat16(x);
    union { __hip_bfloat16 h; unsigned short u; } cv; cv.h = h; return cv.u;
}

__device__ __forceinline__ void load_lds16(const void* g, void* l) {
    __builtin_amdgcn_global_load_lds(
        (const __attribute__((address_space(1))) void*)g,
        (__attribute__((address_space(3))) void*)l, 16, 0, 0);
}

// involution on byte addr: bits 4-6 ^= row&7 (rows are 128B apart)
__device__ __forceinline__ int swz(int lin) { return lin ^ (((lin >> 7) & 7) << 4); }

// ------------- kernel 0: fused prep ----------------------------------------
// blocks 0..511   : gather+cast W[sampled] -> Wg bf16, compute adj (2 rows/blk)
// blocks 512..2559: true logits (f32) + cast y_pred -> bf16 (4 rows/blk)
__global__ __launch_bounds__(256) void prep_kernel(
    const int* __restrict__ y_true, const float* __restrict__ y_pred,
    const float* __restrict__ W, const float* __restrict__ b,
    const int* __restrict__ sampled,
    unsigned short* __restrict__ Wg, float* __restrict__ adj,
    float* __restrict__ true_out, unsigned short* __restrict__ ypredB)
{
    int bid = blockIdx.x;
    if (bid < 512) {
        int row = bid * 2 + (threadIdx.x >> 7);   // 0..1023
        int t   = threadIdx.x & 127;              // 128 threads * 4 elems
        if (t == 0) {
            if (row < S_SAMPLED) {
                int c = sampled[row];
                adj[row] = b[c] + neg_log_expected(c);
            } else adj[row] = -1e30f;
        }
        unsigned short* dst = Wg + (size_t)row * DIM + t * 4;
        if (row < S_SAMPLED) {
            float4 f = *(const float4*)(W + (size_t)sampled[row] * DIM + t * 4);
            ushort4 o;
            o.x = f2bf(f.x); o.y = f2bf(f.y); o.z = f2bf(f.z); o.w = f2bf(f.w);
            *(ushort4*)dst = o;
        } else {
            *(ushort4*)dst = make_ushort4(0, 0, 0, 0);
        }
    } else {
        int row  = (bid - 512) * 4 + (threadIdx.x >> 6);
        int lane = threadIdx.x & 63;
        int lab  = y_true[row];
        const float4* ap = (const float4*)(y_pred + (size_t)row * DIM);
        const float4* wp = (const float4*)(W + (size_t)lab * DIM);
        float s = 0.f;
#pragma unroll
        for (int u = 0; u < 2; ++u) {
            float4 a = ap[lane + u * 64];
            float4 w = wp[lane + u * 64];
            s += a.x * w.x + a.y * w.y + a.z * w.z + a.w * w.w;
            ushort4 o;
            o.x = f2bf(a.x); o.y = f2bf(a.y); o.z = f2bf(a.z); o.w = f2bf(a.w);
            *(ushort4*)(ypredB + (size_t)row * DIM + (lane + u * 64) * 4) = o;
        }
#pragma unroll
        for (int off = 32; off; off >>= 1) s += __shfl_xor(s, off);
        if (lane == 0) true_out[row] = s + b[lab] + neg_log_expected(lab);
    }
}

// ------------- kernel 1: MFMA GEMM + per-chunk partial LSE ------------------
// 1-D grid 256 blocks (XCD-swizzled), 512 threads = 8 waves (4 Mwaves x 2 Nwaves)
__global__ __launch_bounds__(512, 2) void gemm_partial_kernel(
    const unsigned short* __restrict__ Abf,   // y_pred bf16 [BATCH][DIM]
    const unsigned short* __restrict__ Wg,    // gathered W bf16 [SPAD][DIM]
    const int*   __restrict__ sampled,
    const float* __restrict__ adj,
    const int*   __restrict__ y_true,
    float*       __restrict__ pmax,           // [BATCH][NCHUNK]
    float*       __restrict__ psum)           // [BATCH][NCHUNK]
{
    __shared__ __align__(16) char smem[98304 + 2048];
    char* As0 = smem;
    char* As1 = smem + 16384;
    char* Bs0 = smem + 32768;
    char* Bs1 = smem + 65536;
    float* redm = (float*)(smem + 98304);          // [2][128]
    float* reds = (float*)(smem + 98304 + 1024);   // [2][128]

    // XCD-aware remap: dispatch i -> XCD i%8; give each XCD 8 full A-stripes
    // (all 4 n-chunks of a stripe on one XCD -> A read from HBM once per chip)
    int wg = blockIdx.x;
    int sw = (wg & 7) * 32 + (wg >> 3);     // bijective, 256 blocks
    const int m0 = (sw >> 2) * BM;
    const int n0 = (sw & 3) * BN;

    const int tid  = threadIdx.x;
    const int lane = tid & 63;
    const int wid  = tid >> 6;
    const int wr   = wid >> 1;
    const int wc   = wid & 1;
    const int g    = lane >> 4;
    const int lcol = lane & 15;

    const char* AB = (const char*)Abf;
    const char* WB = (const char*)Wg;

    // staging: linear LDS dest (tid*16), source pre-inverse-swizzled (rule #21)
    int a_src[2], b_src[4];
#pragma unroll
    for (int it = 0; it < 2; ++it) {
        int d = it * 8192 + tid * 16;
        int row = d >> 7;
        int kb  = (d & 127) ^ ((row & 7) << 4);
        a_src[it] = (m0 + row) * (DIM * 2) + kb;
    }
#pragma unroll
    for (int it = 0; it < 4; ++it) {
        int d = it * 8192 + tid * 16;
        int col = d >> 7;
        int kb  = (d & 127) ^ ((col & 7) << 4);
        b_src[it] = (n0 + col) * (DIM * 2) + kb;
    }

    int a_roff[2][2], b_roff[8][2];
#pragma unroll
    for (int mi = 0; mi < 2; ++mi)
#pragma unroll
        for (int ks = 0; ks < 2; ++ks)
            a_roff[mi][ks] = swz((wr * 32 + mi * 16 + lcol) * 128 + ks * 64 + g * 16);
#pragma unroll
    for (int nj = 0; nj < 8; ++nj)
#pragma unroll
        for (int ks = 0; ks < 2; ++ks)
            b_roff[nj][ks] = swz((wc * 128 + nj * 16 + lcol) * 128 + ks * 64 + g * 16);

    f32x4_t acc[2][8] = {};

#define STAGE(AsP, BsP, kt) do {                                     \
        int kb_ = (kt) * (BKT * 2);                                  \
        load_lds16(AB + a_src[0] + kb_, (AsP) + wid * 1024);         \
        load_lds16(AB + a_src[1] + kb_, (AsP) + 8192 + wid * 1024);  \
        load_lds16(WB + b_src[0] + kb_, (BsP) + wid * 1024);         \
        load_lds16(WB + b_src[1] + kb_, (BsP) + 8192 + wid * 1024);  \
        load_lds16(WB + b_src[2] + kb_, (BsP) + 16384 + wid * 1024); \
        load_lds16(WB + b_src[3] + kb_, (BsP) + 24576 + wid * 1024); \
    } while (0)

#define COMPUTE(AsP, BsP) do {                                                        \
        _Pragma("unroll")                                                             \
        for (int ks = 0; ks < 2; ++ks) {                                              \
            short8_t a0 = *(const short8_t*)((AsP) + a_roff[0][ks]);                  \
            short8_t a1 = *(const short8_t*)((AsP) + a_roff[1][ks]);                  \
            _Pragma("unroll")                                                         \
            for (int nj = 0; nj < 8; ++nj) {                                          \
                short8_t bv = *(const short8_t*)((BsP) + b_roff[nj][ks]);             \
                acc[0][nj] = __builtin_amdgcn_mfma_f32_16x16x32_bf16(a0, bv, acc[0][nj], 0, 0, 0); \
                acc[1][nj] = __builtin_amdgcn_mfma_f32_16x16x32_bf16(a1, bv, acc[1][nj], 0, 0, 0); \
            }                                                                         \
        }                                                                             \
    } while (0)

    // ---- K loop: counted-vmcnt double-buffer (T3/T4), raw barriers ----
    __builtin_amdgcn_sched_barrier(0);
    STAGE(As0, Bs0, 0);
    STAGE(As1, Bs1, 1);
#pragma unroll
    for (int t = 0; t < KTILES; ++t) {
        // wait for tile t's 6 loads; leave tile t+1's 6 in flight
        if (t < KTILES - 1) asm volatile("s_waitcnt vmcnt(6)" ::: "memory");
        else                asm volatile("s_waitcnt vmcnt(0)" ::: "memory");
        __builtin_amdgcn_s_barrier();
        __builtin_amdgcn_sched_barrier(0);
        const char* AsP = (t & 1) ? As1 : As0;
        const char* BsP = (t & 1) ? Bs1 : Bs0;
        __builtin_amdgcn_s_setprio(1);
        COMPUTE(AsP, BsP);
        __builtin_amdgcn_s_setprio(0);
        __builtin_amdgcn_sched_barrier(0);
        __builtin_amdgcn_s_barrier();
        if (t + 2 < KTILES) STAGE((t & 1) ? As1 : As0, (t & 1) ? Bs1 : Bs0, t + 2);
    }
    __builtin_amdgcn_sched_barrier(0);

    // ---- epilogue: adj + hit mask, per-chunk partial (max, sumexp) ----
    // C layout: col = lane&15, row = (lane>>4)*4 + r
    int   labs[2][4];
    float mrow[2][4];
#pragma unroll
    for (int mi = 0; mi < 2; ++mi)
#pragma unroll
        for (int r = 0; r < 4; ++r) {
            labs[mi][r] = y_true[m0 + wr * 32 + mi * 16 + g * 4 + r];
            mrow[mi][r] = -3e38f;
        }

    float ajv[8]; int scv[8];
#pragma unroll
    for (int nj = 0; nj < 8; ++nj) {
        int cg = n0 + wc * 128 + nj * 16 + lcol;
        ajv[nj] = adj[cg];
        scv[nj] = (cg < S_SAMPLED) ? sampled[cg] : -2147483647;
    }

#pragma unroll
    for (int mi = 0; mi < 2; ++mi)
#pragma unroll
        for (int nj = 0; nj < 8; ++nj) {
            f32x4_t v = acc[mi][nj];
#pragma unroll
            for (int r = 0; r < 4; ++r) {
                float x = v[r] + ajv[nj];
                if (scv[nj] == labs[mi][r]) x -= 1e9f;
                v[r] = x;
                mrow[mi][r] = fmaxf(mrow[mi][r], x);
            }
            acc[mi][nj] = v;
        }

#pragma unroll
    for (int s = 1; s < 16; s <<= 1)
#pragma unroll
        for (int mi = 0; mi < 2; ++mi)
#pragma unroll
            for (int r = 0; r < 4; ++r)
                mrow[mi][r] = fmaxf(mrow[mi][r], __shfl_xor(mrow[mi][r], s));
    if (lcol == 0) {
#pragma unroll
        for (int mi = 0; mi < 2; ++mi)
#pragma unroll
            for (int r = 0; r < 4; ++r)
                redm[wc * 128 + wr * 32 + mi * 16 + g * 4 + r] = mrow[mi][r];
    }
    __syncthreads();

    float srow[2][4];
#pragma unroll
    for (int mi = 0; mi < 2; ++mi)
#pragma unroll
        for (int r = 0; r < 4; ++r) {
            int row = wr * 32 + mi * 16 + g * 4 + r;
            float cm = fmaxf(redm[row], redm[128 + row]);
            float s = 0.f;
#pragma unroll
            for (int nj = 0; nj < 8; ++nj)
                s += expf(acc[mi][nj][r] - cm);
            srow[mi][r] = s;
        }
#pragma unroll
    for (int s = 1; s < 16; s <<= 1)
#pragma unroll
        for (int mi = 0; mi < 2; ++mi)
#pragma unroll
            for (int r = 0; r < 4; ++r)
                srow[mi][r] += __shfl_xor(srow[mi][r], s);
    if (lcol == 0) {
#pragma unroll
        for (int mi = 0; mi < 2; ++mi)
#pragma unroll
            for (int r = 0; r < 4; ++r)
                reds[wc * 128 + wr * 32 + mi * 16 + g * 4 + r] = srow[mi][r];
    }
    __syncthreads();

    if (tid < BM) {
        int row = tid;
        float pm = fmaxf(redm[row], redm[128 + row]);
        float ps = reds[row] + reds[128 + row];
        pmax[(size_t)(m0 + row) * NCHUNK + (sw & 3)] = pm;
        psum[(size_t)(m0 + row) * NCHUNK + (sw & 3)] = ps;
    }
#undef STAGE
#undef COMPUTE
}

// ------------- kernel 2: merge partials + mean (single block) ---------------
__global__ __launch_bounds__(1024) void finalize_kernel(
    const float* __restrict__ pmax, const float* __restrict__ psum,
    const float* __restrict__ true_v, float* __restrict__ out)
{
    __shared__ float sm[1024];
    float tot = 0.f;
#pragma unroll
    for (int u = 0; u < BATCH / 1024; ++u) {
        int r = u * 1024 + threadIdx.x;
        float4 pm = *(const float4*)(pmax + (size_t)r * 4);
        float4 ps = *(const float4*)(psum + (size_t)r * 4);
        float t = true_v[r];
        float m = fmaxf(fmaxf(fmaxf(pm.x, pm.y), fmaxf(pm.z, pm.w)), t);
        float s = ps.x * expf(pm.x - m) + ps.y * expf(pm.y - m)
                + ps.z * expf(pm.z - m) + ps.w * expf(pm.w - m)
                + expf(t - m);
        tot += m + logf(s) - t;
    }
    sm[threadIdx.x] = tot;
    __syncthreads();
    for (int st = 512; st; st >>= 1) {
        if (threadIdx.x < st) sm[threadIdx.x] += sm[threadIdx.x + st];
        __syncthreads();
    }
    if (threadIdx.x == 0) out[0] = sm[0] / (float)BATCH;
}

extern "C" void kernel_launch(void* const* d_in, const int* in_sizes, int n_in,
                              void* d_out, int out_size, void* d_ws, size_t ws_size,
                              hipStream_t stream) {
    const int*   y_true  = (const int*)d_in[0];
    const float* y_pred  = (const float*)d_in[1];
    const float* W       = (const float*)d_in[2];
    const float* b       = (const float*)d_in[3];
    const int*   sampled = (const int*)d_in[4];

    char* ws = (char*)d_ws;
    unsigned short* ypredB = (unsigned short*)ws;                        // 8 MB
    unsigned short* Wg     = (unsigned short*)(ws + 8388608);            // 1 MB
    float* adj    = (float*)(ws + 9437184);                              // 4 KB
    float* true_v = (float*)(ws + 9441280);                              // 32 KB
    float* pmax   = (float*)(ws + 9474048);                              // 128 KB
    float* psum   = (float*)(ws + 9605120);                              // 128 KB

    prep_kernel<<<2560, 256, 0, stream>>>(y_true, y_pred, W, b, sampled,
                                          Wg, adj, true_v, ypredB);
    gemm_partial_kernel<<<256, 512, 0, stream>>>(ypredB, Wg, sampled, adj,
                                                 y_true, pmax, psum);
    finalize_kernel<<<1, 1024, 0, stream>>>(pmax, psum, true_v, (float*)d_out);
}